// Round 11
// baseline (182.320 us; speedup 1.0000x reference)
//
#include <hip/hip_runtime.h>

// out[n][p][m] = sum_c x[n][c][p] * rm[n][c][m]
// N=16, C=64, P=65536, M=128. Memory-bound: 256MB read + 512MB write -> floor ~122us.
// v11: VGPR-free staging via global_load_lds (raw fp32, [c][p] linear LDS, 32KB
//      exact) + A-frags direct from global (v8-validated) -> no r[8], no lds_rm.
//      Register demand ~60-70 fits lb(256,5) cap 102 WITHOUT spill -> 5 blocks/CU
//      (grid 1280). f2bf conversion moved to compute-side LDS reads (v4/v10
//      proved LDS/VALU mix is off the critical path). 2 barriers/tile as v4.
//      Rationale: v6 = clean 4/3 slowdown at 3 blk/CU -> wave-concurrency-bound;
//      v5/v7/v9's 5-block attempts all spilled (caps 85/102 vs demand 110-120).

#define NB   16
#define CDIM 64
#define PDIM 65536
#define MDIM 128
#define PT   128
#define NWIN 512          // PDIM / PT
#define WSTRIDE 80        // 1280 blocks / 16 n
#define GRID (NB * WSTRIDE)

typedef __attribute__((ext_vector_type(8))) short bf16x8;
typedef __attribute__((ext_vector_type(4))) float f32x4;

__device__ __forceinline__ unsigned short f2bf(float f) {
  union { float f; unsigned int u; } v; v.f = f;
  unsigned int u = v.u;
  u += 0x7fffu + ((u >> 16) & 1u);  // RNE
  return (unsigned short)(u >> 16);
}

// pack two fp32 -> two bf16 (RNE) in one u32 (lo = first element)
__device__ __forceinline__ unsigned int pack2bf(float flo, float fhi) {
  union { float f; unsigned int u; } a, b;
  a.f = flo; b.f = fhi;
  unsigned int ua = a.u + (0x7fffu + ((a.u >> 16) & 1u));
  unsigned int ub = b.u + (0x7fffu + ((b.u >> 16) & 1u));
  return (ua >> 16) | (ub & 0xffff0000u);
}

union pk8 { bf16x8 f; unsigned int u[4]; };

__global__ __launch_bounds__(256, 5) void nlsa_kernel(
    const float* __restrict__ x, const float* __restrict__ rm,
    float* __restrict__ out) {
  __shared__ float lds_xf[CDIM * PT];   // [c][p] fp32 LINEAR, exactly 32KB

  const int t = threadIdx.x;
  const int b = blockIdx.x;
  const int n  = b & 15;           // constant n per block
  const int w0 = b >> 4;           // first p-window, stride WSTRIDE

  const float* xn   = x  + (size_t)n * CDIM * PDIM;
  const float* rmn  = rm + (size_t)n * CDIM * MDIM;
  float*       outn = out + (size_t)n * PDIM * MDIM;

  const int w_ = t >> 6;    // wave: m range [32w_, 32w_+32); stages c rows [16w_,16w_+16)
  const int l  = t & 63;
  const int lo = l & 15;
  const int g  = l >> 4;

  // ---- A fragments (rm) straight from global, once (v8-validated).
  // A[m][c]: m = w_*32 + mt*16 + lo, c = ks*32 + g*8 + i.
  bf16x8 a[2][2];
  {
    const float* rs = rmn + (size_t)(g * 8) * MDIM + w_ * 32 + lo;
#pragma unroll
    for (int mt = 0; mt < 2; ++mt)
#pragma unroll
      for (int ks = 0; ks < 2; ++ks) {
        float v[8];
#pragma unroll
        for (int i = 0; i < 8; ++i)
          v[i] = rs[(size_t)(ks * 32 + i) * MDIM + mt * 16];
        pk8 p;
#pragma unroll
        for (int j = 0; j < 4; ++j) p.u[j] = pack2bf(v[2 * j], v[2 * j + 1]);
        a[mt][ks] = p.f;
      }
  }

  // per-lane DMA source offset (in floats): row (l>>5), p-offset 4*(l&31)
  const size_t lane_off = (size_t)(l >> 5) * PDIM + (l & 31) * 4;

  for (int w = w0; w < NWIN; w += WSTRIDE) {
    // barrier1: all waves done reading lds_xf for the previous tile
    asm volatile("" ::: "memory");
    __builtin_amdgcn_s_barrier();
    asm volatile("" ::: "memory");

    // ---- stage tile w: 8x global_load_lds_dwordx4 per wave, no VGPR staging.
    // instr i writes c-rows {16w_+2i, 16w_+2i+1} linearly (1KB contiguous LDS).
    {
      const float* gbase = xn + (size_t)w * PT + lane_off;
#pragma unroll
      for (int i = 0; i < 8; ++i) {
        const int c0 = 16 * w_ + 2 * i;
        const float* gp = gbase + (size_t)c0 * PDIM;         // per-lane source
        float* lp = &lds_xf[c0 * PT];                        // wave-uniform dest
        __builtin_amdgcn_global_load_lds(
            (const __attribute__((address_space(1))) unsigned int*)gp,
            (__attribute__((address_space(3))) unsigned int*)lp, 16, 0, 0);
      }
    }
    // own DMAs (and older output stores) complete, then all-wave visibility
    asm volatile("s_waitcnt vmcnt(0)" ::: "memory");
    __builtin_amdgcn_s_barrier();
    asm volatile("" ::: "memory");

    // ---- compute tile w: B-frags gathered from fp32 LDS, f2bf on the fly
    const int p_base = w * PT;
#pragma unroll
    for (int pt_ = 0; pt_ < 8; ++pt_) {
      const int prow = pt_ * 16 + lo;
      pk8 b0, b1;
#pragma unroll
      for (int j = 0; j < 4; ++j) {
        b0.u[j] = pack2bf(lds_xf[(g * 8 + 2 * j) * PT + prow],
                          lds_xf[(g * 8 + 2 * j + 1) * PT + prow]);
        b1.u[j] = pack2bf(lds_xf[(32 + g * 8 + 2 * j) * PT + prow],
                          lds_xf[(32 + g * 8 + 2 * j + 1) * PT + prow]);
      }
      f32x4 acc0 = {0.f, 0.f, 0.f, 0.f};
      f32x4 acc1 = {0.f, 0.f, 0.f, 0.f};
      acc0 = __builtin_amdgcn_mfma_f32_16x16x32_bf16(a[0][0], b0.f, acc0, 0, 0, 0);
      acc0 = __builtin_amdgcn_mfma_f32_16x16x32_bf16(a[0][1], b1.f, acc0, 0, 0, 0);
      acc1 = __builtin_amdgcn_mfma_f32_16x16x32_bf16(a[1][0], b0.f, acc1, 0, 0, 0);
      acc1 = __builtin_amdgcn_mfma_f32_16x16x32_bf16(a[1][1], b1.f, acc1, 0, 0, 0);

      float* dst = outn + (size_t)(p_base + prow) * MDIM + w_ * 32 + g * 4;
      *(f32x4*)(dst)      = acc0;   // m = 32w_ + 4g + {0..3}
      *(f32x4*)(dst + 16) = acc1;   // m = 32w_ + 16 + 4g + {0..3}
    }
  }
}

extern "C" void kernel_launch(void* const* d_in, const int* in_sizes, int n_in,
                              void* d_out, int out_size, void* d_ws, size_t ws_size,
                              hipStream_t stream) {
  const float* x  = (const float*)d_in[0];   // (N, C, H, W) fp32
  const float* rm = (const float*)d_in[1];   // (N, C, M) fp32
  float* out = (float*)d_out;                // (N, P, M) fp32
  nlsa_kernel<<<dim3(GRID), dim3(256), 0, stream>>>(x, rm, out);
}

// Round 12
// 176.131 us; speedup vs baseline: 1.0351x; 1.0351x over previous
//
#include <hip/hip_runtime.h>

// out[n][p][m] = sum_c x[n][c][p] * rm[n][c][m]
// N=16, C=64, P=65536, M=128. Memory-bound: 256MB read + 512MB write -> floor ~122us.
// v12: T3/T4 pattern -- double-buffered global_load_lds staging with COUNTED
//      vmcnt (never 0). PT=64, buf[2][64c][64p] fp32 = 32KB LDS, A-frags direct
//      from global, grid 1024 (4 blocks/CU). Per tile/wave: 4 DMA + 8 stores.
//      In-order vmcnt math: after issuing DMA_{k+2}, wait vmcnt(8) ==> DMA_{k+1}
//      retired (8 = stores_k; DMAs+stores issued after it cover the window),
//      loads stay in flight across both barriers; no lgkm drains anywhere.
//      v11's lesson: per-tile vmcnt(0) drain cost ~0 -> read latency hidden;
//      v4/v10: LDS/VALU mix off-path. This removes the last phase coupling.

#define NB   16
#define CDIM 64
#define PDIM 65536
#define MDIM 128
#define PT   64
#define BLOCKS_PER_N 64
#define P_PER_BLOCK 1024
#define TILES 16          // P_PER_BLOCK / PT

typedef __attribute__((ext_vector_type(8))) short bf16x8;
typedef __attribute__((ext_vector_type(4))) float f32x4;

// pack two fp32 -> two bf16 (RNE) in one u32 (lo = first element)
__device__ __forceinline__ unsigned int pack2bf(float flo, float fhi) {
  union { float f; unsigned int u; } a, b;
  a.f = flo; b.f = fhi;
  unsigned int ua = a.u + (0x7fffu + ((a.u >> 16) & 1u));
  unsigned int ub = b.u + (0x7fffu + ((b.u >> 16) & 1u));
  return (ua >> 16) | (ub & 0xffff0000u);
}

union pk8 { bf16x8 f; unsigned int u[4]; };

__global__ __launch_bounds__(256, 4) void nlsa_kernel(
    const float* __restrict__ x, const float* __restrict__ rm,
    float* __restrict__ out) {
  __shared__ float lds_xf[2][CDIM * PT];   // [c][p] fp32 linear, 2 x 16KB

  const int t = threadIdx.x;
  const int b = blockIdx.x;
  const int n  = b >> 6;
  const int bt = b & 63;

  const float* xn   = x  + (size_t)n * CDIM * PDIM;
  const float* rmn  = rm + (size_t)n * CDIM * MDIM;
  float*       outn = out + (size_t)n * PDIM * MDIM;

  const int w_ = t >> 6;    // wave: m range [32w_, 32w_+32); stages c rows [16w_,16w_+16)
  const int l  = t & 63;
  const int lo = l & 15;
  const int g  = l >> 4;

  // ---- A fragments (rm) straight from global, once (validated v8/v9/v11).
  // A[m][c]: m = w_*32 + mt*16 + lo, c = ks*32 + g*8 + i.
  bf16x8 a[2][2];
  {
    const float* rs = rmn + (size_t)(g * 8) * MDIM + w_ * 32 + lo;
#pragma unroll
    for (int mt = 0; mt < 2; ++mt)
#pragma unroll
      for (int ks = 0; ks < 2; ++ks) {
        float v[8];
#pragma unroll
        for (int i = 0; i < 8; ++i)
          v[i] = rs[(size_t)(ks * 32 + i) * MDIM + mt * 16];
        pk8 p;
#pragma unroll
        for (int j = 0; j < 4; ++j) p.u[j] = pack2bf(v[2 * j], v[2 * j + 1]);
        a[mt][ks] = p.f;
      }
  }

  // ---- DMA staging of tile kk into buf[kk&1]: 4 x global_load_lds_dwordx4.
  // instr i: wave w_ stages c-rows [16w_+4i, 16w_+4i+4) x 64p (1KB linear LDS).
  // lane l -> lds byte base+16l = row c0 + (l>>4), p = (l&15)*4  == source map.
  const size_t lane_off = (size_t)(l >> 4) * PDIM + (l & 15) * 4;

#define STAGE(kk)                                                             \
  {                                                                           \
    const float* gb = xn + (size_t)bt * P_PER_BLOCK + (kk) * PT + lane_off +  \
                      (size_t)(16 * w_) * PDIM;                               \
    float* lb = &lds_xf[(kk) & 1][16 * w_ * PT];                              \
    _Pragma("unroll")                                                         \
    for (int i = 0; i < 4; ++i) {                                             \
      __builtin_amdgcn_global_load_lds(                                       \
          (const __attribute__((address_space(1))) unsigned int*)             \
              (gb + (size_t)(4 * i) * PDIM),                                  \
          (__attribute__((address_space(3))) unsigned int*)(lb + 4 * i * PT), \
          16, 0, 0);                                                          \
    }                                                                         \
  }

  // prologue: fill both buffers; vmcnt(4) => tile-0 DMAs + A-loads retired.
  STAGE(0)
  STAGE(1)
  asm volatile("s_waitcnt vmcnt(4)" ::: "memory");
  __builtin_amdgcn_s_barrier();
  asm volatile("" ::: "memory");

  for (int kk = 0; kk < TILES; ++kk) {
    const float* cur = &lds_xf[kk & 1][0];
    const int p_base = bt * P_PER_BLOCK + kk * PT;

    // ---- compute tile kk: B-frags from fp32 LDS (f2bf on the fly), 8 stores
#pragma unroll
    for (int pt_ = 0; pt_ < 4; ++pt_) {
      const int prow = pt_ * 16 + lo;
      pk8 b0, b1;
#pragma unroll
      for (int j = 0; j < 4; ++j) {
        b0.u[j] = pack2bf(cur[(g * 8 + 2 * j) * PT + prow],
                          cur[(g * 8 + 2 * j + 1) * PT + prow]);
        b1.u[j] = pack2bf(cur[(32 + g * 8 + 2 * j) * PT + prow],
                          cur[(32 + g * 8 + 2 * j + 1) * PT + prow]);
      }
      f32x4 acc0 = {0.f, 0.f, 0.f, 0.f};
      f32x4 acc1 = {0.f, 0.f, 0.f, 0.f};
      acc0 = __builtin_amdgcn_mfma_f32_16x16x32_bf16(a[0][0], b0.f, acc0, 0, 0, 0);
      acc0 = __builtin_amdgcn_mfma_f32_16x16x32_bf16(a[0][1], b1.f, acc0, 0, 0, 0);
      acc1 = __builtin_amdgcn_mfma_f32_16x16x32_bf16(a[1][0], b0.f, acc1, 0, 0, 0);
      acc1 = __builtin_amdgcn_mfma_f32_16x16x32_bf16(a[1][1], b1.f, acc1, 0, 0, 0);

      float* dst = outn + (size_t)(p_base + prow) * MDIM + w_ * 32 + g * 4;
      *(f32x4*)(dst)      = acc0;   // m = 32w_ + 4g + {0..3}
      *(f32x4*)(dst + 16) = acc1;   // m = 32w_ + 16 + 4g + {0..3}
    }

    // barrier A: all waves done READING buf[kk&1] (no waitcnt attached)
    asm volatile("" ::: "memory");
    __builtin_amdgcn_s_barrier();
    asm volatile("" ::: "memory");

    // refill the just-freed buffer with tile kk+2 (loads fly across barriers)
    if (kk + 2 < TILES) STAGE(kk + 2)

    // counted wait: ops issued after DMA_{kk+1} = 8 stores (+4 DMA_{kk+2}), so
    // <=8 outstanding ==> DMA_{kk+1} retired. Never drains to 0.
    asm volatile("s_waitcnt vmcnt(8)" ::: "memory");
    __builtin_amdgcn_s_barrier();   // barrier B: buf[(kk+1)&1] visible to all
    asm volatile("" ::: "memory");
  }
#undef STAGE
}

extern "C" void kernel_launch(void* const* d_in, const int* in_sizes, int n_in,
                              void* d_out, int out_size, void* d_ws, size_t ws_size,
                              hipStream_t stream) {
  const float* x  = (const float*)d_in[0];   // (N, C, H, W) fp32
  const float* rm = (const float*)d_in[1];   // (N, C, M) fp32
  float* out = (float*)d_out;                // (N, P, M) fp32
  nlsa_kernel<<<dim3(NB * BLOCKS_PER_N), dim3(256), 0, stream>>>(x, rm, out);
}